// Round 9
// baseline (47.245 us; speedup 1.0000x reference)
//
#include <hip/hip_runtime.h>

#define NF   784
#define ZD   64
#define BXN  256
#define BZN  4096
#define KDIM 3136    // 4*NF
#define LCOL 1568    // 2*NF logit columns

typedef __attribute__((ext_vector_type(8))) short bf16x8;
typedef __attribute__((ext_vector_type(4))) float f32x4;
typedef __attribute__((ext_vector_type(8))) unsigned short ushort8;

__device__ __forceinline__ unsigned short f2bf(float f) {
  unsigned u = __float_as_uint(f);
  u += 0x7fff + ((u >> 16) & 1);   // round-to-nearest-even
  return (unsigned short)(u >> 16);
}

// ---------------- Kernel 1: prep (fused) ----------------
__global__ __launch_bounds__(256) void prep(const float* __restrict__ x,
                                            const float* __restrict__ z,
                                            const float* __restrict__ W,
                                            const int* __restrict__ tree,
                                            unsigned short* __restrict__ Amat,
                                            unsigned short* __restrict__ zb,
                                            unsigned short* __restrict__ Wt) {
  int bid = blockIdx.x, tid = threadIdx.x;
  if (bid < 1024) {                       // ---- build_a
    int b = bid >> 2;
    int j = (bid & 3) * 256 + tid;
    if (j >= NF) return;
    float xb = x[b * NF + j];
    int idx = tree[j];
    int gidx = idx < 0 ? idx + NF : idx;  // JAX negative-index wrap
    float xt = x[b * NF + gidx];
    ushort4 v;
    v.x = f2bf((1.f - xt) * xb);
    v.y = f2bf(xt * xb);
    v.z = f2bf((1.f - xt) * (1.f - xb));
    v.w = f2bf(xt * (1.f - xb));
    *(ushort4*)&Amat[(size_t)b * KDIM + 4 * j] = v;
  } else if (bid < 1280) {                // ---- z -> bf16
    int t = (bid - 1024) * 256 + tid;
    float4 v = *(const float4*)&z[t * 4];
    ushort4 o = { f2bf(v.x), f2bf(v.y), f2bf(v.z), f2bf(v.w) };
    *(ushort4*)&zb[t * 4] = o;
  } else {                                // ---- W -> Wt (transpose)
    int t = (bid - 1280) * 256 + tid;
    int c = t >> 4, k0 = (t & 15) * 4;
    ushort4 o;
    o.x = f2bf(W[(k0 + 0) * LCOL + c]);
    o.y = f2bf(W[(k0 + 1) * LCOL + c]);
    o.z = f2bf(W[(k0 + 2) * LCOL + c]);
    o.w = f2bf(W[(k0 + 3) * LCOL + c]);
    *(ushort4*)&Wt[c * 64 + k0] = o;
  }
}

// ---------------- Kernel 2: FUSED logits+logsigmoid+GEMM, BK=64, A direct ----------------
// 512 blocks = 64 nt x 8 ks; 256 thr (4 waves). Wave w: output rows [64w,64w+64),
// produces logit z-rows [n0+16w, n0+16w+16). Per step: 64 K = 32 logit cols (2 cg).
// Only B in LDS (dbuf, 1 barrier/step). A-frags from L2, prefetched 1 step ahead.
// 32 main MFMA per wave per barrier (2x R6); drain = 2 ushort8 writes only.
#define LPB 72   // row pitch (shorts): 144 B -> 2-way bank aliasing (free)
__global__ __launch_bounds__(256, 2) void gemm_fused(const unsigned short* __restrict__ Amat,
                                                     const unsigned short* __restrict__ zb,
                                                     const unsigned short* __restrict__ Wt,
                                                     const float* __restrict__ bias,
                                                     const int* __restrict__ tree,
                                                     float* __restrict__ part) {
  __shared__ unsigned short Bs[2][64][LPB];  // 18432 B
  int bid = blockIdx.x;
  int s = bid & 7, nt = bid >> 3;
  int n0 = nt * 64;
  int kt0    = (s == 0) ? 0 : 7 + 6 * (s - 1);   // 49 k64-units = 7 + 6*7
  int nsteps = (s == 0) ? 7 : 6;
  int ktend = kt0 + nsteps;
  int tid = threadIdx.x;
  int w = tid >> 6, lane = tid & 63;
  int fr = lane & 15, hi = lane >> 4, kq = hi * 8;

  // z fragments: this wave's 16 z-rows, K=64, resident all steps.
  const unsigned short* zp = zb + (size_t)(n0 + w * 16 + fr) * 64 + kq;
  bf16x8 zf0 = *(const bf16x8*)zp;
  bf16x8 zf1 = *(const bf16x8*)(zp + 32);

  const unsigned short* Agf = Amat + (size_t)(w * 64 + fr) * KDIM + kq;

  f32x4 acc[4][4];
#pragma unroll
  for (int m = 0; m < 4; ++m)
#pragma unroll
    for (int n = 0; n < 4; ++n) acc[m][n] = (f32x4){0.f, 0.f, 0.f, 0.f};

  // ---- prologue: step kt0 registers
  bf16x8 wfc[2][2]; float4 b4c[2]; int2 trc[2];
#pragma unroll
  for (int cg = 0; cg < 2; ++cg) {
    const unsigned short* wp = Wt + (size_t)(kt0 * 32 + cg * 16 + fr) * 64 + kq;
    wfc[cg][0] = *(const bf16x8*)wp;
    wfc[cg][1] = *(const bf16x8*)(wp + 32);
    b4c[cg] = *(const float4*)&bias[kt0 * 32 + cg * 16 + 4 * hi];
    trc[cg] = *(const int2*)&tree[kt0 * 16 + cg * 8 + 2 * hi];
  }
  bf16x8 ac[4][2];
#pragma unroll
  for (int m = 0; m < 4; ++m)
#pragma unroll
    for (int kc = 0; kc < 2; ++kc)
      ac[m][kc] = *(const bf16x8*)(Agf + (size_t)m * 16 * KDIM + kt0 * 64 + kc * 32);

  int buf = 0;
  for (int i = 0; i < nsteps; ++i) {
    int kt = kt0 + i;
    // --- 1. logit MFMAs for both col-groups (operands in regs)
    f32x4 lacc[2];
#pragma unroll
    for (int cg = 0; cg < 2; ++cg) {
      lacc[cg] = (f32x4){0.f, 0.f, 0.f, 0.f};
      lacc[cg] = __builtin_amdgcn_mfma_f32_16x16x32_bf16(wfc[cg][0], zf0, lacc[cg], 0, 0, 0);
      lacc[cg] = __builtin_amdgcn_mfma_f32_16x16x32_bf16(wfc[cg][1], zf1, lacc[cg], 0, 0, 0);
    }
    // --- 2. prefetch step kt+1 (clamped; unused on last iter)
    int ktn = (kt + 1 < ktend) ? kt + 1 : kt;
    bf16x8 wfn[2][2]; float4 b4n[2]; int2 trn[2];
#pragma unroll
    for (int cg = 0; cg < 2; ++cg) {
      const unsigned short* wpn = Wt + (size_t)(ktn * 32 + cg * 16 + fr) * 64 + kq;
      wfn[cg][0] = *(const bf16x8*)wpn;
      wfn[cg][1] = *(const bf16x8*)(wpn + 32);
      b4n[cg] = *(const float4*)&bias[ktn * 32 + cg * 16 + 4 * hi];
      trn[cg] = *(const int2*)&tree[ktn * 16 + cg * 8 + 2 * hi];
    }
    bf16x8 an[4][2];
#pragma unroll
    for (int m = 0; m < 4; ++m)
#pragma unroll
      for (int kc = 0; kc < 2; ++kc)
        an[m][kc] = *(const bf16x8*)(Agf + (size_t)m * 16 * KDIM + ktn * 64 + kc * 32);
    // --- 3. log-sigmoid epilogue + Bs write (lane: cols kt*32+16cg+4hi+{0..3})
#pragma unroll
    for (int cg = 0; cg < 2; ++cg) {
      float bb[4] = { b4c[cg].x, b4c[cg].y, b4c[cg].z, b4c[cg].w };
      int tt[2] = { trc[cg].x, trc[cg].y };
      ushort8 v;
#pragma unroll
      for (int p = 0; p < 2; ++p) {
        float l1 = lacc[cg][2 * p + 1] + bb[2 * p + 1];
        float l0 = (tt[p] == -1) ? l1 : (lacc[cg][2 * p] + bb[2 * p]);
        float e0 = __expf(-fabsf(l0)); float sp0 = __logf(1.f + e0);
        float ls0 = (l0 >= 0.f) ? -sp0 : l0 - sp0;
        float e1 = __expf(-fabsf(l1)); float sp1 = __logf(1.f + e1);
        float ls1 = (l1 >= 0.f) ? -sp1 : l1 - sp1;
        v[4 * p + 0] = f2bf(ls0);
        v[4 * p + 1] = f2bf(ls1);
        v[4 * p + 2] = f2bf(ls0 - l0);
        v[4 * p + 3] = f2bf(ls1 - l1);
      }
      *(ushort8*)&Bs[buf][w * 16 + fr][cg * 32 + kq] = v;  // k-slots 32cg+8hi ✓
    }
    __syncthreads();          // dbuf + single barrier per step
    // --- 4. main MFMA: 32 per wave (2 k-chunks x 4m x 4n)
#pragma unroll
    for (int kc = 0; kc < 2; ++kc) {
      bf16x8 b[4];
#pragma unroll
      for (int n = 0; n < 4; ++n)
        b[n] = *(const bf16x8*)&Bs[buf][n * 16 + fr][kc * 32 + kq];
#pragma unroll
      for (int m = 0; m < 4; ++m)
#pragma unroll
        for (int n = 0; n < 4; ++n)
          acc[m][n] = __builtin_amdgcn_mfma_f32_16x16x32_bf16(ac[m][kc], b[n], acc[m][n], 0, 0, 0);
    }
    // --- 5. rotate
#pragma unroll
    for (int cg = 0; cg < 2; ++cg) {
      wfc[cg][0] = wfn[cg][0]; wfc[cg][1] = wfn[cg][1];
      b4c[cg] = b4n[cg]; trc[cg] = trn[cg];
    }
#pragma unroll
    for (int m = 0; m < 4; ++m) {
      ac[m][0] = an[m][0]; ac[m][1] = an[m][1];
    }
    buf ^= 1;
  }
  // C/D: col = fr (n), row = 4hi + r (m). Nontemporal coalesced stores.
  int rq = hi * 4;
  float* Pp = part + (size_t)s * (256 * 4096) + (size_t)(w * 64) * 4096 + n0;
#pragma unroll
  for (int m = 0; m < 4; ++m)
#pragma unroll
    for (int n = 0; n < 4; ++n)
#pragma unroll
      for (int r = 0; r < 4; ++r)
        __builtin_nontemporal_store(acc[m][n][r],
                                    &Pp[(m * 16 + rq + r) * 4096 + n * 16 + fr]);
}

// ---------------- Kernel 3: reduce 8 partials -> d_out (nontemporal streaming) ----------------
__global__ __launch_bounds__(256) void reduce8(const float* __restrict__ part,
                                               float* __restrict__ out) {
  int t = blockIdx.x * 256 + threadIdx.x;  // 262144 threads x float4
  f32x4 s = (f32x4){0.f, 0.f, 0.f, 0.f};
#pragma unroll
  for (int q = 0; q < 8; ++q) {
    const f32x4* p = (const f32x4*)&part[(size_t)q * (256 * 4096) + (size_t)t * 4];
    s += __builtin_nontemporal_load(p);
  }
  f32x4* o = (f32x4*)&out[(size_t)t * 4];
  __builtin_nontemporal_store(s, o);
}

extern "C" void kernel_launch(void* const* d_in, const int* in_sizes, int n_in,
                              void* d_out, int out_size, void* d_ws, size_t ws_size,
                              hipStream_t stream) {
  const float* x    = (const float*)d_in[0];
  const float* z    = (const float*)d_in[1];
  const float* W    = (const float*)d_in[2];
  const float* bias = (const float*)d_in[3];
  const int*   tree = (const int*)d_in[4];
  float* out = (float*)d_out;

  unsigned short* Amat = (unsigned short*)d_ws;                     // 1,605,632 B
  unsigned short* zb   = (unsigned short*)((char*)d_ws + 1605632);  //   524,288 B
  unsigned short* Wt   = (unsigned short*)((char*)d_ws + 2129920);  //   200,704 B
  float*          part = (float*)((char*)d_ws + 2330624);           // 33,554,432 B

  prep<<<dim3(1378), 256, 0, stream>>>(x, z, W, tree, Amat, zb, Wt);
  gemm_fused<<<dim3(512), 256, 0, stream>>>(Amat, zb, Wt, bias, tree, part);
  reduce8<<<dim3(1024), 256, 0, stream>>>(part, out);
}